// Round 1
// baseline (988.329 us; speedup 1.0000x reference)
//
#include <hip/hip_runtime.h>
#include <math.h>

// ---------------------------------------------------------------------------
// AGNN: h1 = relu(x@W1+b1); h2 = agnn(h1, beta=1); h3 = agnn(h2, beta2);
//       out = log_softmax(h3@W2 + b2)
// Strategy: CSR-by-dst built on device each launch (no float atomics),
// wave-per-node conv with online exp accumulation (no segment_max needed:
// logits bounded by |beta|), all-f32 math for round-1 correctness.
// ---------------------------------------------------------------------------

static inline int divup(int a, int b) { return (a + b - 1) / b; }

__device__ __forceinline__ float wave_sum(float p) {
#pragma unroll
    for (int m = 1; m < 64; m <<= 1) p += __shfl_xor(p, m, 64);
    return p;
}

// --- edge dtype detect/convert ---------------------------------------------
// If edge_index is int64 (little-endian), the high word of every value is 0.
__global__ __launch_bounds__(64) void k_detect(const int* __restrict__ raw, int* flag) {
    int t = threadIdx.x;
    int v = raw[2 * t + 1];
    unsigned long long b = __ballot(v != 0);
    if (t == 0) *flag = (b == 0ULL) ? 1 : 0;  // 1 => int64 layout
}

__global__ __launch_bounds__(256) void k_cvt(const int* __restrict__ raw, int E,
                                             const int* __restrict__ flag,
                                             int* __restrict__ s32, int* __restrict__ d32) {
    int i = blockIdx.x * blockDim.x + threadIdx.x;
    if (i >= E) return;
    if (*flag) {
        s32[i] = raw[2 * (size_t)i];
        d32[i] = raw[2 * ((size_t)E + i)];
    } else {
        s32[i] = raw[i];
        d32[i] = raw[(size_t)E + i];
    }
}

// --- CSR build -------------------------------------------------------------
__global__ __launch_bounds__(256) void k_hist(const int* __restrict__ d32, int E, int N,
                                              int* __restrict__ cnt) {
    int e = blockIdx.x * blockDim.x + threadIdx.x;
    if (e >= E + N) return;
    int d = (e < E) ? d32[e] : (e - E);
    atomicAdd(&cnt[d], 1);
}

__global__ __launch_bounds__(1024) void k_scan1(const int* __restrict__ cnt, int N,
                                                int* __restrict__ rp, int* __restrict__ bsum) {
    __shared__ int sm[1024];
    int t = threadIdx.x;
    int i = blockIdx.x * 1024 + t;
    int v = (i < N) ? cnt[i] : 0;
    sm[t] = v;
    __syncthreads();
#pragma unroll
    for (int off = 1; off < 1024; off <<= 1) {
        int u = (t >= off) ? sm[t - off] : 0;
        __syncthreads();
        sm[t] += u;
        __syncthreads();
    }
    if (i < N) rp[i] = sm[t] - v;  // exclusive
    if (t == 1023) bsum[blockIdx.x] = sm[t];
}

__global__ __launch_bounds__(64) void k_scan2(int* __restrict__ bsum, int nb) {
    if (threadIdx.x == 0) {
        int run = 0;
        for (int i = 0; i < nb; ++i) { int v = bsum[i]; bsum[i] = run; run += v; }
    }
}

__global__ __launch_bounds__(256) void k_scan3(int* __restrict__ rp, const int* __restrict__ bsum,
                                               int N, int Etot, int* __restrict__ cursor) {
    int i = blockIdx.x * blockDim.x + threadIdx.x;
    if (i < N) {
        int v = rp[i] + bsum[i >> 10];
        rp[i] = v;
        cursor[i] = v;
    } else if (i == N) {
        rp[N] = Etot;
    }
}

__global__ __launch_bounds__(256) void k_scatter(const int* __restrict__ s32,
                                                 const int* __restrict__ d32, int E, int N,
                                                 int* __restrict__ cursor, int* __restrict__ esrc) {
    int e = blockIdx.x * blockDim.x + threadIdx.x;
    if (e >= E + N) return;
    int s, d;
    if (e < E) { s = s32[e]; d = d32[e]; }
    else       { s = d = e - E; }
    int pos = atomicAdd(&cursor[d], 1);
    esrc[pos] = s;
}

// --- GEMM1: h1 = relu(x @ W1 + b1), x[N,512], W1[512,128] ------------------
__global__ __launch_bounds__(256) void k_gemm1(const float* __restrict__ x,
                                               const float* __restrict__ W1,
                                               const float* __restrict__ b1, int N,
                                               float* __restrict__ h1) {
    __shared__ float As[16][65];   // transposed x tile, padded
    __shared__ float Bs[16][128];
    const int tid = threadIdx.x;
    const int tx = tid & 15, ty = tid >> 4;
    const int r0 = ty * 4, c0 = tx * 8;
    const int row0 = blockIdx.x * 64;
    const int arow = tid >> 2;
    const int ak = (tid & 3) * 4;

    float acc[4][8];
#pragma unroll
    for (int i = 0; i < 4; ++i)
#pragma unroll
        for (int j = 0; j < 8; ++j) acc[i][j] = 0.f;

    for (int k0 = 0; k0 < 512; k0 += 16) {
        float4 av = make_float4(0.f, 0.f, 0.f, 0.f);
        int grow = row0 + arow;
        if (grow < N) av = *(const float4*)&x[(size_t)grow * 512 + k0 + ak];
        float4 bv[2];
#pragma unroll
        for (int i = 0; i < 2; ++i) {
            int f4 = tid + 256 * i;
            int bk = f4 >> 5, bc = (f4 & 31) * 4;
            bv[i] = *(const float4*)&W1[(size_t)(k0 + bk) * 128 + bc];
        }
        __syncthreads();
        As[ak + 0][arow] = av.x; As[ak + 1][arow] = av.y;
        As[ak + 2][arow] = av.z; As[ak + 3][arow] = av.w;
#pragma unroll
        for (int i = 0; i < 2; ++i) {
            int f4 = tid + 256 * i;
            int bk = f4 >> 5, bc = (f4 & 31) * 4;
            *(float4*)&Bs[bk][bc] = bv[i];
        }
        __syncthreads();
#pragma unroll
        for (int k = 0; k < 16; ++k) {
            float aa[4];
            aa[0] = As[k][r0]; aa[1] = As[k][r0 + 1];
            aa[2] = As[k][r0 + 2]; aa[3] = As[k][r0 + 3];
            float4 p0 = *(const float4*)&Bs[k][c0];
            float4 p1 = *(const float4*)&Bs[k][c0 + 4];
            float bb[8] = {p0.x, p0.y, p0.z, p0.w, p1.x, p1.y, p1.z, p1.w};
#pragma unroll
            for (int i = 0; i < 4; ++i)
#pragma unroll
                for (int j = 0; j < 8; ++j) acc[i][j] += aa[i] * bb[j];
        }
        __syncthreads();
    }
    float4 q0 = *(const float4*)&b1[c0];
    float4 q1 = *(const float4*)&b1[c0 + 4];
    float bias[8] = {q0.x, q0.y, q0.z, q0.w, q1.x, q1.y, q1.z, q1.w};
#pragma unroll
    for (int i = 0; i < 4; ++i) {
        int row = row0 + r0 + i;
        if (row < N) {
            float4 o0, o1;
            o0.x = fmaxf(acc[i][0] + bias[0], 0.f);
            o0.y = fmaxf(acc[i][1] + bias[1], 0.f);
            o0.z = fmaxf(acc[i][2] + bias[2], 0.f);
            o0.w = fmaxf(acc[i][3] + bias[3], 0.f);
            o1.x = fmaxf(acc[i][4] + bias[4], 0.f);
            o1.y = fmaxf(acc[i][5] + bias[5], 0.f);
            o1.z = fmaxf(acc[i][6] + bias[6], 0.f);
            o1.w = fmaxf(acc[i][7] + bias[7], 0.f);
            *(float4*)&h1[(size_t)row * 128 + c0] = o0;
            *(float4*)&h1[(size_t)row * 128 + c0 + 4] = o1;
        }
    }
}

// --- inverse norms ---------------------------------------------------------
__global__ __launch_bounds__(256) void k_invnorm(const float* __restrict__ h, int N,
                                                 float* __restrict__ inv) {
    int wid = (blockIdx.x * blockDim.x + threadIdx.x) >> 6;
    int lane = threadIdx.x & 63;
    if (wid >= N) return;
    float2 v = *(const float2*)&h[(size_t)wid * 128 + lane * 2];
    float p = wave_sum(v.x * v.x + v.y * v.y);
    if (lane == 0) inv[wid] = 1.0f / fmaxf(sqrtf(p), 1e-12f);
}

// --- AGNN conv: one wave per dst node --------------------------------------
__global__ __launch_bounds__(256) void k_conv(const float* __restrict__ hin,
                                              const float* __restrict__ inv,
                                              const int* __restrict__ rp,
                                              const int* __restrict__ esrc, int N,
                                              const float* __restrict__ betap,
                                              float* __restrict__ hout) {
    int wid = (blockIdx.x * blockDim.x + threadIdx.x) >> 6;
    int lane = threadIdx.x & 63;
    if (wid >= N) return;
    float beta = betap ? *betap : 1.0f;
    float2 hd = *(const float2*)&hin[(size_t)wid * 128 + lane * 2];
    float invd = inv[wid] * beta;
    int e0 = rp[wid], e1 = rp[wid + 1];
    float ax = 0.f, ay = 0.f, ssum = 0.f;
    for (int e = e0; e < e1; ++e) {
        int s = esrc[e];
        float2 hs = *(const float2*)&hin[(size_t)s * 128 + lane * 2];
        float p = wave_sum(hs.x * hd.x + hs.y * hd.y);
        // logits bounded by |beta| -> exp without max subtraction is safe and
        // mathematically identical after normalization
        float w = __expf(p * invd * inv[s]);
        ssum += w;
        ax += w * hs.x;
        ay += w * hs.y;
    }
    float r = 1.0f / ssum;
    *(float2*)&hout[(size_t)wid * 128 + lane * 2] = make_float2(ax * r, ay * r);
}

// --- GEMM2: logits = h @ W2 + b2, h[N,128], W2[128,64] ---------------------
__global__ __launch_bounds__(256) void k_gemm2(const float* __restrict__ h,
                                               const float* __restrict__ W2,
                                               const float* __restrict__ b2, int N,
                                               float* __restrict__ out) {
    __shared__ float Hs[32][65];
    __shared__ float Ws[32][64];
    const int tid = threadIdx.x;
    const int tx = tid & 15, ty = tid >> 4;
    const int r0 = ty * 4, c0 = tx * 4;
    const int row0 = blockIdx.x * 64;
    float acc[4][4];
#pragma unroll
    for (int i = 0; i < 4; ++i)
#pragma unroll
        for (int j = 0; j < 4; ++j) acc[i][j] = 0.f;

    for (int k0 = 0; k0 < 128; k0 += 32) {
        float4 hv[2], wv[2];
#pragma unroll
        for (int i = 0; i < 2; ++i) {
            int f4 = tid + 256 * i;
            int hrow = f4 >> 3, hk = (f4 & 7) * 4;
            int grow = row0 + hrow;
            hv[i] = (grow < N) ? *(const float4*)&h[(size_t)grow * 128 + k0 + hk]
                               : make_float4(0.f, 0.f, 0.f, 0.f);
            int wk = f4 >> 4, wc = (f4 & 15) * 4;
            wv[i] = *(const float4*)&W2[(size_t)(k0 + wk) * 64 + wc];
        }
        __syncthreads();
#pragma unroll
        for (int i = 0; i < 2; ++i) {
            int f4 = tid + 256 * i;
            int hrow = f4 >> 3, hk = (f4 & 7) * 4;
            Hs[hk + 0][hrow] = hv[i].x; Hs[hk + 1][hrow] = hv[i].y;
            Hs[hk + 2][hrow] = hv[i].z; Hs[hk + 3][hrow] = hv[i].w;
            int wk = f4 >> 4, wc = (f4 & 15) * 4;
            *(float4*)&Ws[wk][wc] = wv[i];
        }
        __syncthreads();
#pragma unroll
        for (int k = 0; k < 32; ++k) {
            float aa[4];
            aa[0] = Hs[k][r0]; aa[1] = Hs[k][r0 + 1];
            aa[2] = Hs[k][r0 + 2]; aa[3] = Hs[k][r0 + 3];
            float4 bq = *(const float4*)&Ws[k][c0];
            float bb[4] = {bq.x, bq.y, bq.z, bq.w};
#pragma unroll
            for (int i = 0; i < 4; ++i)
#pragma unroll
                for (int j = 0; j < 4; ++j) acc[i][j] += aa[i] * bb[j];
        }
        __syncthreads();
    }
    float4 bq = *(const float4*)&b2[c0];
    float bb[4] = {bq.x, bq.y, bq.z, bq.w};
#pragma unroll
    for (int i = 0; i < 4; ++i) {
        int row = row0 + r0 + i;
        if (row < N) {
            float4 o;
            o.x = acc[i][0] + bb[0];
            o.y = acc[i][1] + bb[1];
            o.z = acc[i][2] + bb[2];
            o.w = acc[i][3] + bb[3];
            *(float4*)&out[(size_t)row * 64 + c0] = o;
        }
    }
}

// --- row-wise log_softmax over 64 cols, in place ---------------------------
__global__ __launch_bounds__(256) void k_lsm(float* __restrict__ out, int N) {
    int wid = (blockIdx.x * blockDim.x + threadIdx.x) >> 6;
    int lane = threadIdx.x & 63;
    if (wid >= N) return;
    float v = out[(size_t)wid * 64 + lane];
    float m = v;
#pragma unroll
    for (int s = 1; s < 64; s <<= 1) m = fmaxf(m, __shfl_xor(m, s, 64));
    float ssum = wave_sum(__expf(v - m));
    out[(size_t)wid * 64 + lane] = v - m - logf(ssum);
}

// ---------------------------------------------------------------------------
extern "C" void kernel_launch(void* const* d_in, const int* in_sizes, int n_in,
                              void* d_out, int out_size, void* d_ws, size_t ws_size,
                              hipStream_t stream) {
    const float* x     = (const float*)d_in[0];
    const int*   ei    = (const int*)d_in[1];
    const float* W1    = (const float*)d_in[2];
    const float* b1    = (const float*)d_in[3];
    const float* beta2 = (const float*)d_in[4];
    const float* W2    = (const float*)d_in[5];
    const float* b2    = (const float*)d_in[6];
    float* out = (float*)d_out;

    const int N = in_sizes[0] / 512;
    const int E = in_sizes[1] / 2;
    const int Etot = E + N;

    char* ws = (char*)d_ws;
    size_t off = 0;
    auto alloc = [&](size_t bytes) -> void* {
        void* p = ws + off;
        off = (off + bytes + 511) & ~(size_t)511;
        return p;
    };
    float* h1   = (float*)alloc((size_t)N * 128 * 4);
    float* h2   = (float*)alloc((size_t)N * 128 * 4);
    float* inv1 = (float*)alloc((size_t)N * 4);
    float* inv2 = (float*)alloc((size_t)N * 4);
    int* cnt    = (int*)alloc((size_t)N * 4);
    int* rp     = (int*)alloc((size_t)(N + 1) * 4);
    int* cursor = (int*)alloc((size_t)N * 4);
    int* bsum   = (int*)alloc(4096);
    int* flag   = (int*)alloc(512);
    int* s32    = (int*)alloc((size_t)E * 4);
    int* d32    = (int*)alloc((size_t)E * 4);
    int* esrc   = (int*)alloc((size_t)Etot * 4);
    (void)ws_size; (void)n_in; (void)out_size;

    hipMemsetAsync(cnt, 0, (size_t)N * 4, stream);

    k_detect<<<1, 64, 0, stream>>>(ei, flag);
    k_cvt<<<divup(E, 256), 256, 0, stream>>>(ei, E, flag, s32, d32);
    k_hist<<<divup(Etot, 256), 256, 0, stream>>>(d32, E, N, cnt);
    int nb = divup(N, 1024);
    k_scan1<<<nb, 1024, 0, stream>>>(cnt, N, rp, bsum);
    k_scan2<<<1, 64, 0, stream>>>(bsum, nb);
    k_scan3<<<divup(N + 1, 256), 256, 0, stream>>>(rp, bsum, N, Etot, cursor);
    k_scatter<<<divup(Etot, 256), 256, 0, stream>>>(s32, d32, E, N, cursor, esrc);

    k_gemm1<<<divup(N, 64), 256, 0, stream>>>(x, W1, b1, N, h1);
    k_invnorm<<<divup(N, 4), 256, 0, stream>>>(h1, N, inv1);
    k_conv<<<divup(N, 4), 256, 0, stream>>>(h1, inv1, rp, esrc, N, nullptr, h2);
    k_invnorm<<<divup(N, 4), 256, 0, stream>>>(h2, N, inv2);
    k_conv<<<divup(N, 4), 256, 0, stream>>>(h2, inv2, rp, esrc, N, beta2, h1);
    k_gemm2<<<divup(N, 64), 256, 0, stream>>>(h1, W2, b2, N, out);
    k_lsm<<<divup(N, 4), 256, 0, stream>>>(out, N);
}

// Round 2
// 535.969 us; speedup vs baseline: 1.8440x; 1.8440x over previous
//
#include <hip/hip_runtime.h>
#include <math.h>

// ---------------------------------------------------------------------------
// AGNN round 2: bf16 MFMA for both GEMMs, bf16 feature table for the convs
// (16-lane-per-edge gather, 4 edges/wave-iteration), fused log_softmax.
// All accumulation in f32; bf16 only on storage/matmul inputs (error budget:
// threshold 0.107, round-1 all-f32 absmax was 0.031).
// ---------------------------------------------------------------------------

static inline int divup(int a, int b) { return (a + b - 1) / b; }

typedef __attribute__((ext_vector_type(8))) short short8;
typedef __attribute__((ext_vector_type(4))) float f32x4;
union U16 { uint4 u; short8 s; };

__device__ __forceinline__ unsigned bf16r(float f) {  // f32 -> bf16 bits, RNE
    unsigned u = __float_as_uint(f);
    return (u + 0x7FFFu + ((u >> 16) & 1u)) >> 16;
}
__device__ __forceinline__ unsigned pack2(float a, float b) {
    return bf16r(a) | (bf16r(b) << 16);
}
__device__ __forceinline__ float bflo(unsigned u) { return __uint_as_float(u << 16); }
__device__ __forceinline__ float bfhi(unsigned u) { return __uint_as_float(u & 0xFFFF0000u); }

__device__ __forceinline__ float wave_sum(float p) {
#pragma unroll
    for (int m = 1; m < 64; m <<= 1) p += __shfl_xor(p, m, 64);
    return p;
}

// --- edge dtype detect/convert ---------------------------------------------
__global__ __launch_bounds__(64) void k_detect(const int* __restrict__ raw, int* flag) {
    int t = threadIdx.x;
    int v = raw[2 * t + 1];
    unsigned long long b = __ballot(v != 0);
    if (t == 0) *flag = (b == 0ULL) ? 1 : 0;  // 1 => int64 layout
}

__global__ __launch_bounds__(256) void k_cvt(const int* __restrict__ raw, int E,
                                             const int* __restrict__ flag,
                                             int* __restrict__ s32, int* __restrict__ d32) {
    int i = blockIdx.x * blockDim.x + threadIdx.x;
    if (i >= E) return;
    if (*flag) {
        s32[i] = raw[2 * (size_t)i];
        d32[i] = raw[2 * ((size_t)E + i)];
    } else {
        s32[i] = raw[i];
        d32[i] = raw[(size_t)E + i];
    }
}

// --- CSR build -------------------------------------------------------------
__global__ __launch_bounds__(256) void k_hist(const int* __restrict__ d32, int E, int N,
                                              int* __restrict__ cnt) {
    int e = blockIdx.x * blockDim.x + threadIdx.x;
    if (e >= E + N) return;
    int d = (e < E) ? d32[e] : (e - E);
    atomicAdd(&cnt[d], 1);
}

__global__ __launch_bounds__(1024) void k_scan1(const int* __restrict__ cnt, int N,
                                                int* __restrict__ rp, int* __restrict__ bsum) {
    __shared__ int sm[1024];
    int t = threadIdx.x;
    int i = blockIdx.x * 1024 + t;
    int v = (i < N) ? cnt[i] : 0;
    sm[t] = v;
    __syncthreads();
#pragma unroll
    for (int off = 1; off < 1024; off <<= 1) {
        int u = (t >= off) ? sm[t - off] : 0;
        __syncthreads();
        sm[t] += u;
        __syncthreads();
    }
    if (i < N) rp[i] = sm[t] - v;  // exclusive
    if (t == 1023) bsum[blockIdx.x] = sm[t];
}

__global__ __launch_bounds__(64) void k_scan2(int* __restrict__ bsum, int nb) {
    if (threadIdx.x == 0) {
        int run = 0;
        for (int i = 0; i < nb; ++i) { int v = bsum[i]; bsum[i] = run; run += v; }
    }
}

__global__ __launch_bounds__(256) void k_scan3(int* __restrict__ rp, const int* __restrict__ bsum,
                                               int N, int Etot, int* __restrict__ cursor) {
    int i = blockIdx.x * blockDim.x + threadIdx.x;
    if (i < N) {
        int v = rp[i] + bsum[i >> 10];
        rp[i] = v;
        cursor[i] = v;
    } else if (i == N) {
        rp[N] = Etot;
    }
}

__global__ __launch_bounds__(256) void k_scatter(const int* __restrict__ s32,
                                                 const int* __restrict__ d32, int E, int N,
                                                 int* __restrict__ cursor, int* __restrict__ esrc) {
    int e = blockIdx.x * blockDim.x + threadIdx.x;
    if (e >= E + N) return;
    int s, d;
    if (e < E) { s = s32[e]; d = d32[e]; }
    else       { s = d = e - E; }
    int pos = atomicAdd(&cursor[d], 1);
    esrc[pos] = s;
}

// --- weight preconvert: W1 [512][128] f32 -> W1t [128][512] bf16 -----------
__global__ __launch_bounds__(256) void k_cvtW1(const float* __restrict__ W1,
                                               unsigned short* __restrict__ W1t) {
    int i = blockIdx.x * 256 + threadIdx.x;
    if (i >= 512 * 128) return;
    int k = i >> 7, n = i & 127;
    W1t[n * 512 + k] = (unsigned short)bf16r(W1[i]);
}

// --- W2 [128][64] f32 -> W2t [64][128] bf16 --------------------------------
__global__ __launch_bounds__(256) void k_cvtW2(const float* __restrict__ W2,
                                               unsigned short* __restrict__ W2t) {
    int i = blockIdx.x * 256 + threadIdx.x;
    if (i >= 128 * 64) return;
    int k = i >> 6, n = i & 63;
    W2t[n * 128 + k] = (unsigned short)bf16r(W2[i]);
}

// --- GEMM1 (MFMA): h1 = relu(x @ W1 + b1) -> bf16 [N][128] -----------------
// tile 128x128, BK=64, 4 waves (2x2), each wave 64x64 via 4x4 16x16x32 frags.
// LDS rows padded to 144B (9 x 16B) for uniform bank-quad distribution.
#define G1_ASTRIDE 144
__global__ __launch_bounds__(256) void k_gemm1(const float* __restrict__ x,
                                               const unsigned short* __restrict__ W1t,
                                               const float* __restrict__ b1, int N,
                                               unsigned short* __restrict__ h1) {
    __shared__ __align__(16) unsigned char As[128 * G1_ASTRIDE];
    __shared__ __align__(16) unsigned char Bs[128 * G1_ASTRIDE];
    const int tid = threadIdx.x;
    const int lane = tid & 63;
    const int lt = lane & 15, lg = lane >> 4;
    const int wid = tid >> 6;
    const int wr = wid >> 1, wc = wid & 1;
    const int row0 = blockIdx.x * 128;
    const int arow = tid >> 1, ahalf = tid & 1;

    f32x4 acc[4][4];
#pragma unroll
    for (int i = 0; i < 4; ++i)
#pragma unroll
        for (int j = 0; j < 4; ++j) acc[i][j] = (f32x4){0.f, 0.f, 0.f, 0.f};

    for (int k0 = 0; k0 < 512; k0 += 64) {
        // stage loads to regs
        float4 av[8];
        int grow = row0 + arow;
        const float* xp = x + (size_t)grow * 512 + k0 + ahalf * 32;
#pragma unroll
        for (int i = 0; i < 8; ++i)
            av[i] = (grow < N) ? ((const float4*)xp)[i] : make_float4(0.f, 0.f, 0.f, 0.f);
        uint4 bv[4];
        const unsigned short* wp = W1t + (size_t)arow * 512 + k0 + ahalf * 32;
#pragma unroll
        for (int i = 0; i < 4; ++i) bv[i] = ((const uint4*)wp)[i];

        __syncthreads();  // previous iter's LDS reads done
        {
            unsigned char* ab = As + arow * G1_ASTRIDE + ahalf * 64;
#pragma unroll
            for (int i = 0; i < 4; ++i) {
                uint4 q;
                q.x = pack2(av[2 * i].x, av[2 * i].y);
                q.y = pack2(av[2 * i].z, av[2 * i].w);
                q.z = pack2(av[2 * i + 1].x, av[2 * i + 1].y);
                q.w = pack2(av[2 * i + 1].z, av[2 * i + 1].w);
                ((uint4*)ab)[i] = q;
            }
            unsigned char* bb = Bs + arow * G1_ASTRIDE + ahalf * 64;
#pragma unroll
            for (int i = 0; i < 4; ++i) ((uint4*)bb)[i] = bv[i];
        }
        __syncthreads();

#pragma unroll
        for (int sub = 0; sub < 2; ++sub) {
            U16 af[4], bf[4];
#pragma unroll
            for (int mi = 0; mi < 4; ++mi)
                af[mi].u = *(const uint4*)(As + (wr * 64 + mi * 16 + lt) * G1_ASTRIDE + sub * 64 + lg * 16);
#pragma unroll
            for (int ni = 0; ni < 4; ++ni)
                bf[ni].u = *(const uint4*)(Bs + (wc * 64 + ni * 16 + lt) * G1_ASTRIDE + sub * 64 + lg * 16);
#pragma unroll
            for (int mi = 0; mi < 4; ++mi)
#pragma unroll
                for (int ni = 0; ni < 4; ++ni)
                    acc[mi][ni] = __builtin_amdgcn_mfma_f32_16x16x32_bf16(
                        af[mi].s, bf[ni].s, acc[mi][ni], 0, 0, 0);
        }
    }

    // epilogue: bias + relu + bf16 store
    float bias[4];
#pragma unroll
    for (int ni = 0; ni < 4; ++ni) bias[ni] = b1[wc * 64 + ni * 16 + lt];
#pragma unroll
    for (int mi = 0; mi < 4; ++mi) {
#pragma unroll
        for (int reg = 0; reg < 4; ++reg) {
            int row = row0 + wr * 64 + mi * 16 + lg * 4 + reg;
            if (row < N) {
#pragma unroll
                for (int ni = 0; ni < 4; ++ni) {
                    float v = fmaxf(acc[mi][ni][reg] + bias[ni], 0.f);
                    h1[(size_t)row * 128 + wc * 64 + ni * 16 + lt] = (unsigned short)bf16r(v);
                }
            }
        }
    }
}

// --- inverse norms from bf16 table -----------------------------------------
__global__ __launch_bounds__(256) void k_invnorm(const unsigned short* __restrict__ h, int N,
                                                 float* __restrict__ inv) {
    int wid = (blockIdx.x * blockDim.x + threadIdx.x) >> 6;
    int lane = threadIdx.x & 63;
    if (wid >= N) return;
    unsigned u = *(const unsigned*)&h[(size_t)wid * 128 + lane * 2];
    float a = bflo(u), b = bfhi(u);
    float p = wave_sum(a * a + b * b);
    if (lane == 0) inv[wid] = 1.0f / fmaxf(sqrtf(p), 1e-12f);
}

// --- AGNN conv: wave per dst node, 16 lanes per edge, 4 edges/iteration ----
__global__ __launch_bounds__(256) void k_conv(const unsigned short* __restrict__ hin,
                                              const float* __restrict__ inv,
                                              const int* __restrict__ rp,
                                              const int* __restrict__ esrc, int N,
                                              const float* __restrict__ betap,
                                              unsigned short* __restrict__ hout) {
    int wid = (blockIdx.x * blockDim.x + threadIdx.x) >> 6;
    if (wid >= N) return;
    int lane = threadIdx.x & 63;
    int t = lane & 15, g = lane >> 4;
    float beta = betap ? *betap : 1.0f;

    uint4 hdu = *(const uint4*)&hin[(size_t)wid * 128 + 8 * t];
    float hd[8];
    hd[0] = bflo(hdu.x); hd[1] = bfhi(hdu.x);
    hd[2] = bflo(hdu.y); hd[3] = bfhi(hdu.y);
    hd[4] = bflo(hdu.z); hd[5] = bfhi(hdu.z);
    hd[6] = bflo(hdu.w); hd[7] = bfhi(hdu.w);
    float invd = inv[wid] * beta;

    int e0 = rp[wid], e1 = rp[wid + 1];
    float acc[8] = {0.f, 0.f, 0.f, 0.f, 0.f, 0.f, 0.f, 0.f};
    float ssum = 0.f;

    for (int eb = e0; eb < e1; eb += 4) {
        int e = eb + g;
        int ee = (e < e1) ? e : e0;  // clamp (masked below)
        int s = esrc[ee];
        float is = inv[s];
        uint4 hu = *(const uint4*)&hin[(size_t)s * 128 + 8 * t];
        float v[8];
        v[0] = bflo(hu.x); v[1] = bfhi(hu.x);
        v[2] = bflo(hu.y); v[3] = bfhi(hu.y);
        v[4] = bflo(hu.z); v[5] = bfhi(hu.z);
        v[6] = bflo(hu.w); v[7] = bfhi(hu.w);
        float p = 0.f;
#pragma unroll
        for (int j = 0; j < 8; ++j) p += v[j] * hd[j];
        p += __shfl_xor(p, 1, 64);
        p += __shfl_xor(p, 2, 64);
        p += __shfl_xor(p, 4, 64);
        p += __shfl_xor(p, 8, 64);
        float w = __expf(p * invd * is);
        if (e >= e1) w = 0.f;
        ssum += w;
#pragma unroll
        for (int j = 0; j < 8; ++j) acc[j] += w * v[j];
    }
    // combine the four 16-lane groups (they own the same dims)
#pragma unroll
    for (int j = 0; j < 8; ++j) {
        acc[j] += __shfl_xor(acc[j], 16, 64);
        acc[j] += __shfl_xor(acc[j], 32, 64);
    }
    ssum += __shfl_xor(ssum, 16, 64);
    ssum += __shfl_xor(ssum, 32, 64);
    float r = 1.0f / ssum;
    if (g == 0) {
        uint4 q;
        q.x = pack2(acc[0] * r, acc[1] * r);
        q.y = pack2(acc[2] * r, acc[3] * r);
        q.z = pack2(acc[4] * r, acc[5] * r);
        q.w = pack2(acc[6] * r, acc[7] * r);
        *(uint4*)&hout[(size_t)wid * 128 + 8 * t] = q;
    }
}

// --- GEMM2 (MFMA) + fused log_softmax: out = lsm(h @ W2 + b2) --------------
// tile 128 rows x 64 cols (full), K=128 single pass; 4 waves, wave = 32x64.
#define G2_ASTRIDE 272
__global__ __launch_bounds__(256) void k_gemm2(const unsigned short* __restrict__ h,
                                               const unsigned short* __restrict__ W2t,
                                               const float* __restrict__ b2, int N,
                                               float* __restrict__ out) {
    __shared__ __align__(16) unsigned char As[128 * G2_ASTRIDE];
    __shared__ __align__(16) unsigned char Bs[64 * G2_ASTRIDE];
    const int tid = threadIdx.x;
    const int lane = tid & 63;
    const int lt = lane & 15, lg = lane >> 4;
    const int wid = tid >> 6;
    const int row0 = blockIdx.x * 128;

    // stage A: 128 rows x 256B, 2 threads/row
    {
        int arow = tid >> 1, ahalf = tid & 1;
        const uint4* src = (const uint4*)(h + (size_t)(row0 + arow) * 128 + ahalf * 64);
        unsigned char* ab = As + arow * G2_ASTRIDE + ahalf * 128;
#pragma unroll
        for (int i = 0; i < 8; ++i) ((uint4*)ab)[i] = src[i];
        // stage B: 64 rows x 256B, 4 threads/row
        int brow = tid >> 2, bq = tid & 3;
        const uint4* bs = (const uint4*)(W2t + (size_t)brow * 128 + bq * 32);
        unsigned char* bb = Bs + brow * G2_ASTRIDE + bq * 64;
#pragma unroll
        for (int i = 0; i < 4; ++i) ((uint4*)bb)[i] = bs[i];
    }
    __syncthreads();

    f32x4 acc[2][4];
#pragma unroll
    for (int i = 0; i < 2; ++i)
#pragma unroll
        for (int j = 0; j < 4; ++j) acc[i][j] = (f32x4){0.f, 0.f, 0.f, 0.f};

#pragma unroll
    for (int sub = 0; sub < 4; ++sub) {
        U16 af[2], bf[4];
#pragma unroll
        for (int mi = 0; mi < 2; ++mi)
            af[mi].u = *(const uint4*)(As + (wid * 32 + mi * 16 + lt) * G2_ASTRIDE + sub * 64 + lg * 16);
#pragma unroll
        for (int ni = 0; ni < 4; ++ni)
            bf[ni].u = *(const uint4*)(Bs + (ni * 16 + lt) * G2_ASTRIDE + sub * 64 + lg * 16);
#pragma unroll
        for (int mi = 0; mi < 2; ++mi)
#pragma unroll
            for (int ni = 0; ni < 4; ++ni)
                acc[mi][ni] = __builtin_amdgcn_mfma_f32_16x16x32_bf16(
                    af[mi].s, bf[ni].s, acc[mi][ni], 0, 0, 0);
    }

    float bias[4];
#pragma unroll
    for (int ni = 0; ni < 4; ++ni) bias[ni] = b2[ni * 16 + lt];

    // fused log_softmax: each 16-lane group owns complete 64-col rows
#pragma unroll
    for (int mi = 0; mi < 2; ++mi) {
#pragma unroll
        for (int reg = 0; reg < 4; ++reg) {
            int row = row0 + wid * 32 + mi * 16 + lg * 4 + reg;
            if (row < N) {
                float v[4];
#pragma unroll
                for (int ni = 0; ni < 4; ++ni) v[ni] = acc[mi][ni][reg] + bias[ni];
                float m = fmaxf(fmaxf(v[0], v[1]), fmaxf(v[2], v[3]));
                m = fmaxf(m, __shfl_xor(m, 1, 64));
                m = fmaxf(m, __shfl_xor(m, 2, 64));
                m = fmaxf(m, __shfl_xor(m, 4, 64));
                m = fmaxf(m, __shfl_xor(m, 8, 64));
                float s = __expf(v[0] - m) + __expf(v[1] - m) +
                          __expf(v[2] - m) + __expf(v[3] - m);
                s += __shfl_xor(s, 1, 64);
                s += __shfl_xor(s, 2, 64);
                s += __shfl_xor(s, 4, 64);
                s += __shfl_xor(s, 8, 64);
                float lg2 = logf(s);
#pragma unroll
                for (int ni = 0; ni < 4; ++ni)
                    out[(size_t)row * 64 + ni * 16 + lt] = v[ni] - m - lg2;
            }
        }
    }
}

// ---------------------------------------------------------------------------
extern "C" void kernel_launch(void* const* d_in, const int* in_sizes, int n_in,
                              void* d_out, int out_size, void* d_ws, size_t ws_size,
                              hipStream_t stream) {
    const float* x     = (const float*)d_in[0];
    const int*   ei    = (const int*)d_in[1];
    const float* W1    = (const float*)d_in[2];
    const float* b1    = (const float*)d_in[3];
    const float* beta2 = (const float*)d_in[4];
    const float* W2    = (const float*)d_in[5];
    const float* b2    = (const float*)d_in[6];
    float* out = (float*)d_out;

    const int N = in_sizes[0] / 512;
    const int E = in_sizes[1] / 2;
    const int Etot = E + N;

    char* ws = (char*)d_ws;
    size_t off = 0;
    auto alloc = [&](size_t bytes) -> void* {
        void* p = ws + off;
        off = (off + bytes + 511) & ~(size_t)511;
        return p;
    };
    unsigned short* h1b = (unsigned short*)alloc((size_t)N * 128 * 2);
    unsigned short* h2b = (unsigned short*)alloc((size_t)N * 128 * 2);
    float* inv1 = (float*)alloc((size_t)N * 4);
    float* inv2 = (float*)alloc((size_t)N * 4);
    int* cnt    = (int*)alloc((size_t)N * 4);
    int* rp     = (int*)alloc((size_t)(N + 1) * 4);
    int* cursor = (int*)alloc((size_t)N * 4);
    int* bsum   = (int*)alloc(4096);
    int* flag   = (int*)alloc(512);
    unsigned short* W1t = (unsigned short*)alloc(512 * 128 * 2);
    unsigned short* W2t = (unsigned short*)alloc(128 * 64 * 2);
    int* s32    = (int*)alloc((size_t)E * 4);
    int* d32    = (int*)alloc((size_t)E * 4);
    int* esrc   = (int*)alloc((size_t)Etot * 4);
    (void)ws_size; (void)n_in; (void)out_size;

    hipMemsetAsync(cnt, 0, (size_t)N * 4, stream);

    k_detect<<<1, 64, 0, stream>>>(ei, flag);
    k_cvt<<<divup(E, 256), 256, 0, stream>>>(ei, E, flag, s32, d32);
    k_hist<<<divup(Etot, 256), 256, 0, stream>>>(d32, E, N, cnt);
    int nb = divup(N, 1024);
    k_scan1<<<nb, 1024, 0, stream>>>(cnt, N, rp, bsum);
    k_scan2<<<1, 64, 0, stream>>>(bsum, nb);
    k_scan3<<<divup(N + 1, 256), 256, 0, stream>>>(rp, bsum, N, Etot, cursor);
    k_scatter<<<divup(Etot, 256), 256, 0, stream>>>(s32, d32, E, N, cursor, esrc);

    k_cvtW1<<<divup(512 * 128, 256), 256, 0, stream>>>(W1, W1t);
    k_cvtW2<<<divup(128 * 64, 256), 256, 0, stream>>>(W2, W2t);

    k_gemm1<<<divup(N, 128), 256, 0, stream>>>(x, W1t, b1, N, h1b);
    k_invnorm<<<divup(N, 4), 256, 0, stream>>>(h1b, N, inv1);
    k_conv<<<divup(N, 4), 256, 0, stream>>>(h1b, inv1, rp, esrc, N, nullptr, h2b);
    k_invnorm<<<divup(N, 4), 256, 0, stream>>>(h2b, N, inv2);
    k_conv<<<divup(N, 4), 256, 0, stream>>>(h2b, inv2, rp, esrc, N, beta2, h1b);
    k_gemm2<<<divup(N, 128), 256, 0, stream>>>(h1b, W2t, b2, N, out);
}

// Round 5
// 432.942 us; speedup vs baseline: 2.2828x; 1.2380x over previous
//
#include <hip/hip_runtime.h>
#include <math.h>

// ---------------------------------------------------------------------------
// AGNN round 4 (bugfix of r3b): GEMM1 epilogue stored only 16 of each
// thread's 32 row elements (uint4 o[2] overflowed by the 16-word pack loop).
// Now o[4] / dst[0..3]. Rest identical to r3b:
//  - XCD-partitioned scatter
//  - double-buffered XOR-swizzled MFMA GEMM1 with fused row-normalize
//  - normalized feature tables (x_hat bf16 + norm f32)
//  - MFMA GEMM2 with fused log_softmax
// ---------------------------------------------------------------------------

static inline int divup(int a, int b) { return (a + b - 1) / b; }

typedef __attribute__((ext_vector_type(8))) short short8;
typedef __attribute__((ext_vector_type(4))) float f32x4;
union U16 { uint4 u; short8 s; };

__device__ __forceinline__ unsigned bf16r(float f) {  // f32 -> bf16 bits, RNE
    unsigned u = __float_as_uint(f);
    return (u + 0x7FFFu + ((u >> 16) & 1u)) >> 16;
}
__device__ __forceinline__ unsigned pack2(float a, float b) {
    return bf16r(a) | (bf16r(b) << 16);
}
__device__ __forceinline__ float bflo(unsigned u) { return __uint_as_float(u << 16); }
__device__ __forceinline__ float bfhi(unsigned u) { return __uint_as_float(u & 0xFFFF0000u); }

// --- edge dtype detect / convert (+histogram fold) -------------------------
__global__ __launch_bounds__(64) void k_detect(const int* __restrict__ raw, int* flag) {
    int t = threadIdx.x;
    int v = raw[2 * t + 1];
    unsigned long long b = __ballot(v != 0);
    if (t == 0) *flag = (b == 0ULL) ? 1 : 0;  // 1 => int64 layout
}

__global__ __launch_bounds__(256) void k_cvt(const int* __restrict__ raw, int E,
                                             const int* __restrict__ flag,
                                             int* __restrict__ s32, int* __restrict__ d32,
                                             int* __restrict__ cnt) {
    int i = blockIdx.x * blockDim.x + threadIdx.x;
    if (i >= E) return;
    int s, d;
    if (*flag) {
        s = raw[2 * (size_t)i];
        d = raw[2 * ((size_t)E + i)];
    } else {
        s = raw[i];
        d = raw[(size_t)E + i];
    }
    s32[i] = s;
    d32[i] = d;
    atomicAdd(&cnt[d], 1);
}

// --- CSR scan (cnt + 1 self-loop per node) ---------------------------------
__global__ __launch_bounds__(1024) void k_scan1(const int* __restrict__ cnt, int N,
                                                int* __restrict__ rp, int* __restrict__ bsum) {
    __shared__ int sm[1024];
    int t = threadIdx.x;
    int i = blockIdx.x * 1024 + t;
    int v = (i < N) ? cnt[i] + 1 : 0;  // +1: self-loop
    sm[t] = v;
    __syncthreads();
#pragma unroll
    for (int off = 1; off < 1024; off <<= 1) {
        int u = (t >= off) ? sm[t - off] : 0;
        __syncthreads();
        sm[t] += u;
        __syncthreads();
    }
    if (i < N) rp[i] = sm[t] - v;  // exclusive
    if (t == 1023) bsum[blockIdx.x] = sm[t];
}

__global__ __launch_bounds__(64) void k_scan2(int* __restrict__ bsum, int nb) {
    if (threadIdx.x == 0) {
        int run = 0;
        for (int i = 0; i < nb; ++i) { int v = bsum[i]; bsum[i] = run; run += v; }
    }
}

__global__ __launch_bounds__(256) void k_scan3(int* __restrict__ rp, const int* __restrict__ bsum,
                                               int N, int Etot, int* __restrict__ cursor) {
    int i = blockIdx.x * blockDim.x + threadIdx.x;
    if (i < N) {
        int v = rp[i] + bsum[i >> 10];
        rp[i] = v;
        cursor[i] = v;
    } else if (i == N) {
        rp[N] = Etot;
    }
}

// --- XCD-partitioned scatter -----------------------------------------------
__global__ __launch_bounds__(256) void k_scatter(const int* __restrict__ s32,
                                                 const int* __restrict__ d32, int E, int N,
                                                 int* __restrict__ cursor,
                                                 int* __restrict__ esrc) {
    int b = blockIdx.x;
    int xcd = b & 7;
    int nstripe = gridDim.x >> 3;
    int stripe = b >> 3;
    int lo = (int)(((long long)xcd * N) >> 3);
    int hi = (int)(((long long)(xcd + 1) * N) >> 3);
    int Etot = E + N;
    for (int e = stripe * 256 + threadIdx.x; e < Etot; e += nstripe * 256) {
        int d = (e < E) ? d32[e] : (e - E);
        if (d < lo || d >= hi) continue;
        int s = (e < E) ? s32[e] : d;
        int pos = atomicAdd(&cursor[d], 1);
        esrc[pos] = s;
    }
}

// --- weight preconvert -----------------------------------------------------
__global__ __launch_bounds__(256) void k_cvtW1(const float* __restrict__ W1,
                                               unsigned short* __restrict__ W1t) {
    int i = blockIdx.x * 256 + threadIdx.x;
    if (i >= 512 * 128) return;
    int k = i >> 7, n = i & 127;
    W1t[n * 512 + k] = (unsigned short)bf16r(W1[i]);
}

__global__ __launch_bounds__(256) void k_cvtW2(const float* __restrict__ W2,
                                               unsigned short* __restrict__ W2t) {
    int i = blockIdx.x * 256 + threadIdx.x;
    if (i >= 128 * 64) return;
    int k = i >> 6, n = i & 63;
    W2t[n * 128 + k] = (unsigned short)bf16r(W2[i]);
}

// --- GEMM1: x_hat1/norm1 = normalize(relu(x @ W1 + b1)) --------------------
#define XS(row, off) ((off) ^ (((row) & 7) << 4))
__global__ __launch_bounds__(256) void k_gemm1(const float* __restrict__ x,
                                               const unsigned short* __restrict__ W1t,
                                               const float* __restrict__ b1, int N,
                                               unsigned short* __restrict__ xh1,
                                               float* __restrict__ n1) {
    __shared__ __align__(16) unsigned char lds[65536];
    const int tid = threadIdx.x;
    const int lane = tid & 63;
    const int lt = lane & 15, lg = lane >> 4;
    const int wid = tid >> 6;
    const int wr = wid >> 1, wc = wid & 1;
    const int row0 = blockIdx.x * 128;
    const int arow = tid >> 1, ahalf = tid & 1;

    f32x4 acc[4][4];
#pragma unroll
    for (int i = 0; i < 4; ++i)
#pragma unroll
        for (int j = 0; j < 4; ++j) acc[i][j] = (f32x4){0.f, 0.f, 0.f, 0.f};

    float4 av[8];
    uint4 bv[4];
    const int grow = row0 + arow;
    const bool aok = grow < N;

    auto issue = [&](int k0) {
        const float* xp = x + (size_t)grow * 512 + k0 + ahalf * 32;
#pragma unroll
        for (int i = 0; i < 8; ++i)
            av[i] = aok ? ((const float4*)xp)[i] : make_float4(0.f, 0.f, 0.f, 0.f);
        const unsigned short* wp = W1t + (size_t)arow * 512 + k0 + ahalf * 32;
#pragma unroll
        for (int i = 0; i < 4; ++i) bv[i] = ((const uint4*)wp)[i];
    };
    auto commit = [&](int buf) {
        unsigned char* ab = lds + buf * 32768 + arow * 128;
#pragma unroll
        for (int i = 0; i < 4; ++i) {
            uint4 q;
            q.x = pack2(av[2 * i].x, av[2 * i].y);
            q.y = pack2(av[2 * i].z, av[2 * i].w);
            q.z = pack2(av[2 * i + 1].x, av[2 * i + 1].y);
            q.w = pack2(av[2 * i + 1].z, av[2 * i + 1].w);
            *(uint4*)(ab + XS(arow, ahalf * 64 + i * 16)) = q;
        }
        unsigned char* bb = lds + 16384 + buf * 32768 + arow * 128;
#pragma unroll
        for (int i = 0; i < 4; ++i)
            *(uint4*)(bb + XS(arow, ahalf * 64 + i * 16)) = bv[i];
    };

    issue(0);
    commit(0);
    __syncthreads();

    for (int t = 0; t < 8; ++t) {
        const int cur = t & 1;
        if (t < 7) issue((t + 1) * 64);
        unsigned char* Acur = lds + cur * 32768;
        unsigned char* Bcur = lds + 16384 + cur * 32768;
#pragma unroll
        for (int sub = 0; sub < 2; ++sub) {
            U16 af[4], bf[4];
#pragma unroll
            for (int mi = 0; mi < 4; ++mi) {
                int r = wr * 64 + mi * 16 + lt;
                af[mi].u = *(const uint4*)(Acur + r * 128 + XS(r, sub * 64 + lg * 16));
            }
#pragma unroll
            for (int ni = 0; ni < 4; ++ni) {
                int r = wc * 64 + ni * 16 + lt;
                bf[ni].u = *(const uint4*)(Bcur + r * 128 + XS(r, sub * 64 + lg * 16));
            }
#pragma unroll
            for (int mi = 0; mi < 4; ++mi)
#pragma unroll
                for (int ni = 0; ni < 4; ++ni)
                    acc[mi][ni] = __builtin_amdgcn_mfma_f32_16x16x32_bf16(
                        af[mi].s, bf[ni].s, acc[mi][ni], 0, 0, 0);
        }
        if (t < 7) {
            commit(cur ^ 1);
            __syncthreads();
        }
    }

    // epilogue: bias+relu -> LDS rows -> norm -> x_hat bf16 + norm f32
    float bias[4];
#pragma unroll
    for (int ni = 0; ni < 4; ++ni) bias[ni] = b1[wc * 64 + ni * 16 + lt];
    float* sc = (float*)lds;  // 64 rows x 132 f32 = 33792B
#pragma unroll 1
    for (int c = 0; c < 2; ++c) {
        __syncthreads();
        if (wr == c) {
#pragma unroll
            for (int mi = 0; mi < 4; ++mi)
#pragma unroll
                for (int reg = 0; reg < 4; ++reg) {
                    int rl = mi * 16 + lg * 4 + reg;
#pragma unroll
                    for (int ni = 0; ni < 4; ++ni)
                        sc[rl * 132 + wc * 64 + ni * 16 + lt] =
                            fmaxf(acc[mi][ni][reg] + bias[ni], 0.f);
                }
        }
        __syncthreads();
        {
            int rl = tid >> 2, q = tid & 3;
            int gr = row0 + c * 64 + rl;
            const float* rowp = sc + rl * 132 + q * 32;
            float v[32];
#pragma unroll
            for (int i = 0; i < 8; ++i) {
                float4 f = ((const float4*)rowp)[i];
                v[4 * i] = f.x; v[4 * i + 1] = f.y; v[4 * i + 2] = f.z; v[4 * i + 3] = f.w;
            }
            float s2 = 0.f;
#pragma unroll
            for (int i = 0; i < 32; ++i) s2 += v[i] * v[i];
            s2 += __shfl_xor(s2, 1, 64);
            s2 += __shfl_xor(s2, 2, 64);
            float nrm = sqrtf(s2);
            float rn = 1.0f / fmaxf(nrm, 1e-12f);
            if (gr < N) {
                uint4 o[4];  // 32 bf16 = 64B (r3b bug: was o[2], overflowed)
                unsigned* op = (unsigned*)o;
#pragma unroll
                for (int i = 0; i < 16; ++i)
                    op[i] = pack2(v[2 * i] * rn, v[2 * i + 1] * rn);
                uint4* dst = (uint4*)(xh1 + (size_t)gr * 128 + q * 32);
                dst[0] = o[0];
                dst[1] = o[1];
                dst[2] = o[2];
                dst[3] = o[3];
                if (q == 0) n1[gr] = nrm;
            }
        }
    }
}

// --- AGNN conv on normalized tables ----------------------------------------
__global__ __launch_bounds__(256) void k_conv(const unsigned short* __restrict__ xh,
                                              const float* __restrict__ nrmt,
                                              const int* __restrict__ rp,
                                              const int* __restrict__ esrc, int N,
                                              const float* __restrict__ betap,
                                              unsigned short* __restrict__ outh,
                                              float* __restrict__ outn) {
    int node = (blockIdx.x * blockDim.x + threadIdx.x) >> 6;
    if (node >= N) return;
    int lane = threadIdx.x & 63;
    int t = lane & 15, g = lane >> 4;
    float beta = betap ? *betap : 1.0f;

    uint4 hdu = *(const uint4*)&xh[(size_t)node * 128 + 8 * t];
    float hd[8];
    hd[0] = bflo(hdu.x); hd[1] = bfhi(hdu.x);
    hd[2] = bflo(hdu.y); hd[3] = bfhi(hdu.y);
    hd[4] = bflo(hdu.z); hd[5] = bfhi(hdu.z);
    hd[6] = bflo(hdu.w); hd[7] = bfhi(hdu.w);

    int e0 = rp[node], e1 = rp[node + 1];
    float acc[8] = {0.f, 0.f, 0.f, 0.f, 0.f, 0.f, 0.f, 0.f};
    float ssum = 0.f;

    for (int eb = e0; eb < e1; eb += 4) {
        int e = eb + g;
        int ee = (e < e1) ? e : e0;
        int s = esrc[ee];
        float ns = nrmt[s];
        uint4 hu = *(const uint4*)&xh[(size_t)s * 128 + 8 * t];
        float v[8];
        v[0] = bflo(hu.x); v[1] = bfhi(hu.x);
        v[2] = bflo(hu.y); v[3] = bfhi(hu.y);
        v[4] = bflo(hu.z); v[5] = bfhi(hu.z);
        v[6] = bflo(hu.w); v[7] = bfhi(hu.w);
        float p = 0.f;
#pragma unroll
        for (int j = 0; j < 8; ++j) p += v[j] * hd[j];
        p += __shfl_xor(p, 1, 64);
        p += __shfl_xor(p, 2, 64);
        p += __shfl_xor(p, 4, 64);
        p += __shfl_xor(p, 8, 64);
        float w = (e < e1) ? __expf(p * beta) : 0.f;
        float wn = w * ns;
        ssum += w;
#pragma unroll
        for (int j = 0; j < 8; ++j) acc[j] += wn * v[j];
    }
#pragma unroll
    for (int j = 0; j < 8; ++j) {
        acc[j] += __shfl_xor(acc[j], 16, 64);
        acc[j] += __shfl_xor(acc[j], 32, 64);
    }
    ssum += __shfl_xor(ssum, 16, 64);
    ssum += __shfl_xor(ssum, 32, 64);
    float r = 1.0f / ssum;

    if (outn == nullptr) {
        if (g == 0) {
            uint4 q;
            q.x = pack2(acc[0] * r, acc[1] * r);
            q.y = pack2(acc[2] * r, acc[3] * r);
            q.z = pack2(acc[4] * r, acc[5] * r);
            q.w = pack2(acc[6] * r, acc[7] * r);
            *(uint4*)&outh[(size_t)node * 128 + 8 * t] = q;
        }
    } else {
        float o[8];
        float s2 = 0.f;
#pragma unroll
        for (int j = 0; j < 8; ++j) { o[j] = acc[j] * r; s2 += o[j] * o[j]; }
        s2 += __shfl_xor(s2, 1, 64);
        s2 += __shfl_xor(s2, 2, 64);
        s2 += __shfl_xor(s2, 4, 64);
        s2 += __shfl_xor(s2, 8, 64);
        float nn = sqrtf(s2);
        float rn = 1.0f / fmaxf(nn, 1e-12f);
        if (g == 0) {
            uint4 q;
            q.x = pack2(o[0] * rn, o[1] * rn);
            q.y = pack2(o[2] * rn, o[3] * rn);
            q.z = pack2(o[4] * rn, o[5] * rn);
            q.w = pack2(o[6] * rn, o[7] * rn);
            *(uint4*)&outh[(size_t)node * 128 + 8 * t] = q;
            if (t == 0) outn[node] = nn;
        }
    }
}

// --- GEMM2 (MFMA) + fused log_softmax --------------------------------------
#define G2_ASTRIDE 272
__global__ __launch_bounds__(256) void k_gemm2(const unsigned short* __restrict__ h,
                                               const unsigned short* __restrict__ W2t,
                                               const float* __restrict__ b2, int N,
                                               float* __restrict__ out) {
    __shared__ __align__(16) unsigned char As[128 * G2_ASTRIDE];
    __shared__ __align__(16) unsigned char Bs[64 * G2_ASTRIDE];
    const int tid = threadIdx.x;
    const int lane = tid & 63;
    const int lt = lane & 15, lg = lane >> 4;
    const int wid = tid >> 6;
    const int row0 = blockIdx.x * 128;

    {
        int arow = tid >> 1, ahalf = tid & 1;
        const uint4* src = (const uint4*)(h + (size_t)(row0 + arow) * 128 + ahalf * 64);
        unsigned char* ab = As + arow * G2_ASTRIDE + ahalf * 128;
#pragma unroll
        for (int i = 0; i < 8; ++i) ((uint4*)ab)[i] = src[i];
        int brow = tid >> 2, bq = tid & 3;
        const uint4* bs = (const uint4*)(W2t + (size_t)brow * 128 + bq * 32);
        unsigned char* bb = Bs + brow * G2_ASTRIDE + bq * 64;
#pragma unroll
        for (int i = 0; i < 4; ++i) ((uint4*)bb)[i] = bs[i];
    }
    __syncthreads();

    f32x4 acc[2][4];
#pragma unroll
    for (int i = 0; i < 2; ++i)
#pragma unroll
        for (int j = 0; j < 4; ++j) acc[i][j] = (f32x4){0.f, 0.f, 0.f, 0.f};

#pragma unroll
    for (int sub = 0; sub < 4; ++sub) {
        U16 af[2], bf[4];
#pragma unroll
        for (int mi = 0; mi < 2; ++mi)
            af[mi].u = *(const uint4*)(As + (wid * 32 + mi * 16 + lt) * G2_ASTRIDE + sub * 64 + lg * 16);
#pragma unroll
        for (int ni = 0; ni < 4; ++ni)
            bf[ni].u = *(const uint4*)(Bs + (ni * 16 + lt) * G2_ASTRIDE + sub * 64 + lg * 16);
#pragma unroll
        for (int mi = 0; mi < 2; ++mi)
#pragma unroll
            for (int ni = 0; ni < 4; ++ni)
                acc[mi][ni] = __builtin_amdgcn_mfma_f32_16x16x32_bf16(
                    af[mi].s, bf[ni].s, acc[mi][ni], 0, 0, 0);
    }

    float bias[4];
#pragma unroll
    for (int ni = 0; ni < 4; ++ni) bias[ni] = b2[ni * 16 + lt];

#pragma unroll
    for (int mi = 0; mi < 2; ++mi) {
#pragma unroll
        for (int reg = 0; reg < 4; ++reg) {
            int row = row0 + wid * 32 + mi * 16 + lg * 4 + reg;
            if (row < N) {
                float v[4];
#pragma unroll
                for (int ni = 0; ni < 4; ++ni) v[ni] = acc[mi][ni][reg] + bias[ni];
                float m = fmaxf(fmaxf(v[0], v[1]), fmaxf(v[2], v[3]));
                m = fmaxf(m, __shfl_xor(m, 1, 64));
                m = fmaxf(m, __shfl_xor(m, 2, 64));
                m = fmaxf(m, __shfl_xor(m, 4, 64));
                m = fmaxf(m, __shfl_xor(m, 8, 64));
                float s = __expf(v[0] - m) + __expf(v[1] - m) +
                          __expf(v[2] - m) + __expf(v[3] - m);
                s += __shfl_xor(s, 1, 64);
                s += __shfl_xor(s, 2, 64);
                s += __shfl_xor(s, 4, 64);
                s += __shfl_xor(s, 8, 64);
                float lg2 = logf(s);
#pragma unroll
                for (int ni = 0; ni < 4; ++ni)
                    out[(size_t)row * 64 + ni * 16 + lt] = v[ni] - m - lg2;
            }
        }
    }
}

// ---------------------------------------------------------------------------
extern "C" void kernel_launch(void* const* d_in, const int* in_sizes, int n_in,
                              void* d_out, int out_size, void* d_ws, size_t ws_size,
                              hipStream_t stream) {
    const float* x     = (const float*)d_in[0];
    const int*   ei    = (const int*)d_in[1];
    const float* W1    = (const float*)d_in[2];
    const float* b1    = (const float*)d_in[3];
    const float* beta2 = (const float*)d_in[4];
    const float* W2    = (const float*)d_in[5];
    const float* b2    = (const float*)d_in[6];
    float* out = (float*)d_out;

    const int N = in_sizes[0] / 512;
    const int E = in_sizes[1] / 2;
    const int Etot = E + N;

    char* ws = (char*)d_ws;
    size_t off = 0;
    auto alloc = [&](size_t bytes) -> void* {
        void* p = ws + off;
        off = (off + bytes + 511) & ~(size_t)511;
        return p;
    };
    unsigned short* t1 = (unsigned short*)alloc((size_t)N * 128 * 2);  // x_hat1 / h3
    unsigned short* t2 = (unsigned short*)alloc((size_t)N * 128 * 2);  // x_hat2
    float* n1   = (float*)alloc((size_t)N * 4);
    float* n2   = (float*)alloc((size_t)N * 4);
    int* cnt    = (int*)alloc((size_t)N * 4);
    int* rp     = (int*)alloc((size_t)(N + 1) * 4);
    int* cursor = (int*)alloc((size_t)N * 4);
    int* bsum   = (int*)alloc(4096);
    int* flag   = (int*)alloc(512);
    unsigned short* W1t = (unsigned short*)alloc(512 * 128 * 2);
    unsigned short* W2t = (unsigned short*)alloc(128 * 64 * 2);
    int* s32    = (int*)alloc((size_t)E * 4);
    int* d32    = (int*)alloc((size_t)E * 4);
    int* esrc   = (int*)alloc((size_t)Etot * 4);
    (void)ws_size; (void)n_in; (void)out_size;

    (void)hipMemsetAsync(cnt, 0, (size_t)N * 4, stream);

    k_detect<<<1, 64, 0, stream>>>(ei, flag);
    k_cvt<<<divup(E, 256), 256, 0, stream>>>(ei, E, flag, s32, d32, cnt);
    int nb = divup(N, 1024);
    k_scan1<<<nb, 1024, 0, stream>>>(cnt, N, rp, bsum);
    k_scan2<<<1, 64, 0, stream>>>(bsum, nb);
    k_scan3<<<divup(N + 1, 256), 256, 0, stream>>>(rp, bsum, N, Etot, cursor);
    k_scatter<<<2048, 256, 0, stream>>>(s32, d32, E, N, cursor, esrc);

    k_cvtW1<<<divup(512 * 128, 256), 256, 0, stream>>>(W1, W1t);
    k_cvtW2<<<divup(128 * 64, 256), 256, 0, stream>>>(W2, W2t);

    k_gemm1<<<divup(N, 128), 256, 0, stream>>>(x, W1t, b1, N, t1, n1);
    k_conv<<<divup(N, 4), 256, 0, stream>>>(t1, n1, rp, esrc, N, nullptr, t2, n2);
    k_conv<<<divup(N, 4), 256, 0, stream>>>(t2, n2, rp, esrc, N, beta2, t1, nullptr);
    k_gemm2<<<divup(N, 128), 256, 0, stream>>>(t1, W2t, b2, N, out);
}